// Round 4
// baseline (822.189 us; speedup 1.0000x reference)
//
#include <hip/hip_runtime.h>

// 32 chained bottleneck blocks on x[16,256,64,64] fp32.
// Phase A: h1_0 = relu(W1_0 x + b1_0)           (reads x once)
// Phase B (x32): h2_k = relu(conv3x3 h1_k), store h2_k;
//                h1_{k+1} = relu(W1_{k+1} relu(W3_k h2_k + b3_k) + b1_{k+1})
//                fused per-pixel; 256-ch tensor never hits memory.
// Phase C: out = sum_k relu(W3_k h2_k + b3_k)   (lane = channel)
//
// R3 lesson: wave-uniform weights through ANY shared per-CU pipe (LDS: 16/34/16
// us for R1/R2/R3) serialize the 4 SIMDs. R4: weights live per-lane in VGPRs
// (36 regs = 4 channels x {w3,b3,w1nT}) and are broadcast with v_readlane --
// pure VALU, no LDS/SMEM pipe in the c-loop.

#define NN 16
#define HH 64
#define WW 64
#define CIN 256
#define CB 4
#define NBLK 32
#define PXT 32  // pixels per phaseC block

__device__ __forceinline__ float rdlane(float v, int l) {
  return __int_as_float(__builtin_amdgcn_readlane(__float_as_int(v), l));
}

// ---------------- Phase A: h1_0 = relu(W1_0 . x + b1_0) ------------------
// grid (64,16): blockIdx.x = y, blockIdx.y = n. 256 threads.
__global__ __launch_bounds__(256) void phaseA(
    const float* __restrict__ x, const float* __restrict__ w1,
    const float* __restrict__ b1, float* __restrict__ h1out) {
  __shared__ float4 w1s[CIN];    // [c] -> o components
  __shared__ float4 part[4][WW]; // [chunk][px] -> o components
  int tid = threadIdx.x;
  for (int i = tid; i < CIN * CB; i += 256) {
    int o = i >> 8, c = i & 255;
    ((float*)&w1s[c])[o] = w1[i]; // w1 global layout [o][c]
  }
  __syncthreads();
  int y = blockIdx.x, n = blockIdx.y;
  int chunk = tid >> 6, px = tid & 63;
  int cbase = chunk * 64;
  const float* xp = x + ((n * CIN + cbase) * HH + y) * WW + px;
  float s0 = 0.f, s1 = 0.f, s2 = 0.f, s3 = 0.f;
#pragma unroll 8
  for (int i = 0; i < 64; ++i) {
    float xv = xp[i * HH * WW];
    float4 wv = w1s[cbase + i];
    s0 = fmaf(xv, wv.x, s0);
    s1 = fmaf(xv, wv.y, s1);
    s2 = fmaf(xv, wv.z, s2);
    s3 = fmaf(xv, wv.w, s3);
  }
  part[chunk][px] = make_float4(s0, s1, s2, s3);
  __syncthreads();
  int px2 = tid >> 2, o = tid & 3;
  float v = ((float*)&part[0][px2])[o] + ((float*)&part[1][px2])[o] +
            ((float*)&part[2][px2])[o] + ((float*)&part[3][px2])[o];
  v += b1[o];
  h1out[((n * HH + y) * WW + px2) * CB + o] = fmaxf(v, 0.f);
}

// ---------------- Phase B: one bottleneck step ---------------------------
// Thread = pixel; 16x16 tile; grid (4,4,16) = 256 blocks (1/CU).
// Fused expand+reduce weights: lane holds 4 channels' packed weights in 36
// VGPRs; broadcast via v_readlane (VALU-only). LDS holds only the h1 tile.
__global__ __launch_bounds__(256, 1) void phaseB(
    const float* __restrict__ h1in, float* __restrict__ h1out,
    float* __restrict__ h2out,
    const float* __restrict__ w2, const float* __restrict__ b2,
    const float* __restrict__ w3, const float* __restrict__ b3,
    const float* __restrict__ w1n, const float* __restrict__ b1n,
    int compute_next) {
  __shared__ float4 h1t[18][18]; // input tile + halo
  int tid = threadIdx.x;
  int tx = blockIdx.x, ty = blockIdx.y, n = blockIdx.z;
  int x0 = tx * 16, y0 = ty * 16;
  int lane = tid & 63;

  // per-lane packed weights for channels c = j*64 + lane
  float wr[4][9];
#pragma unroll
  for (int j = 0; j < 4; ++j) {
    int c = j * 64 + lane;
    float4 a = *(const float4*)&w3[c * 4]; // w3 [c][jout]
    wr[j][0] = a.x; wr[j][1] = a.y; wr[j][2] = a.z; wr[j][3] = a.w;
    wr[j][4] = b3[c];
    wr[j][5] = w1n[c];        // w1n global [o][c]
    wr[j][6] = w1n[256 + c];
    wr[j][7] = w1n[512 + c];
    wr[j][8] = w1n[768 + c];
  }

  // stage input tile with zero halo
  for (int t = tid; t < 324; t += 256) {
    int cy = t / 18, cx = t % 18;
    int gy = y0 + cy - 1, gx = x0 + cx - 1;
    float4 v = make_float4(0.f, 0.f, 0.f, 0.f);
    if (gy >= 0 && gy < HH && gx >= 0 && gx < WW)
      v = *(const float4*)&h1in[((n * HH + gy) * WW + gx) * CB];
    h1t[cy][cx] = v;
  }
  __syncthreads();

  int lx = tid & 15, ly = tid >> 4;

  // 3x3 conv 4->4 + bias + relu; w2 [o][i][p] uniform -> s_load, once/block
  float4 hacc = make_float4(b2[0], b2[1], b2[2], b2[3]);
#pragma unroll
  for (int p = 0; p < 9; ++p) {
    int dy = p / 3, dx = p % 3;
    float4 hv = h1t[ly + dy][lx + dx];
#pragma unroll
    for (int i = 0; i < 4; ++i) {
      float hvi = (i == 0) ? hv.x : (i == 1) ? hv.y : (i == 2) ? hv.z : hv.w;
      hacc.x = fmaf(hvi, w2[(0 * 4 + i) * 9 + p], hacc.x);
      hacc.y = fmaf(hvi, w2[(1 * 4 + i) * 9 + p], hacc.y);
      hacc.z = fmaf(hvi, w2[(2 * 4 + i) * 9 + p], hacc.z);
      hacc.w = fmaf(hvi, w2[(3 * 4 + i) * 9 + p], hacc.w);
    }
  }
  float4 h2 = make_float4(fmaxf(hacc.x, 0.f), fmaxf(hacc.y, 0.f),
                          fmaxf(hacc.z, 0.f), fmaxf(hacc.w, 0.f));

  int gy = y0 + ly, gx = x0 + lx;
  int pxg = (n * HH + gy) * WW + gx;
  *(float4*)&h2out[pxg * CB] = h2;

  // fused expand(W3_k)+relu+reduce(W1_{k+1}); weights via v_readlane.
  float4 t = make_float4(0.f, 0.f, 0.f, 0.f);
#pragma unroll
  for (int j = 0; j < 4; ++j) {
#pragma unroll 4
    for (int l = 0; l < 64; ++l) {
      float u = rdlane(wr[j][4], l);
      u = fmaf(h2.x, rdlane(wr[j][0], l), u);
      u = fmaf(h2.y, rdlane(wr[j][1], l), u);
      u = fmaf(h2.z, rdlane(wr[j][2], l), u);
      u = fmaf(h2.w, rdlane(wr[j][3], l), u);
      float v = fmaxf(u, 0.f);
      t.x = fmaf(v, rdlane(wr[j][5], l), t.x);
      t.y = fmaf(v, rdlane(wr[j][6], l), t.y);
      t.z = fmaf(v, rdlane(wr[j][7], l), t.z);
      t.w = fmaf(v, rdlane(wr[j][8], l), t.w);
    }
  }
  if (compute_next) {
    float4 r = make_float4(fmaxf(t.x + b1n[0], 0.f), fmaxf(t.y + b1n[1], 0.f),
                           fmaxf(t.z + b1n[2], 0.f), fmaxf(t.w + b1n[3], 0.f));
    *(float4*)&h1out[pxg * CB] = r;
  }
}

// ---------------- Phase C: acc = sum_k relu(W3_k h2_k + b3_k) ------------
// Lane = channel: tid = c, block covers PXT=32 consecutive pixels. Weights in
// registers (coalesced per-k loads), h2 broadcast from double-buffered LDS.
// Padded LDS transpose for coalesced stores. grid (128, 16).
__global__ __launch_bounds__(256, 4) void phaseC(
    const float* __restrict__ h2buf, const float* __restrict__ w3g,
    const float* __restrict__ b3g, float* __restrict__ out) {
  __shared__ float4 h2s[2][PXT];
  __shared__ float tr[CIN][PXT + 1]; // +1 pad: 2-way bank alias = free
  int tid = threadIdx.x;             // channel c
  int p0 = blockIdx.x * PXT;         // flat pixel y*64+x
  int n = blockIdx.y;
  float acc[PXT];
#pragma unroll
  for (int i = 0; i < PXT; ++i) acc[i] = 0.f;

  if (tid < PXT)
    h2s[0][tid] = *(const float4*)&h2buf[((0 * NN + n) * 4096 + p0 + tid) * 4];
  __syncthreads();

  for (int k = 0; k < NBLK; ++k) {
    float4 wv = *(const float4*)&w3g[(k * 256 + tid) * 4]; // coalesced
    float bv = b3g[k * 256 + tid];
    if (k + 1 < NBLK && tid < PXT)
      h2s[(k + 1) & 1][tid] =
          *(const float4*)&h2buf[(((k + 1) * NN + n) * 4096 + p0 + tid) * 4];
    const float4* hb = h2s[k & 1];
#pragma unroll
    for (int i = 0; i < PXT; ++i) {
      float4 h = hb[i]; // broadcast ds_read_b128
      float u = fmaf(h.w, wv.w,
                fmaf(h.z, wv.z, fmaf(h.y, wv.y, fmaf(h.x, wv.x, bv))));
      acc[i] += fmaxf(u, 0.f);
    }
    __syncthreads();
  }

  // transpose in LDS -> coalesced stores
#pragma unroll
  for (int i = 0; i < PXT; ++i) tr[tid][i] = acc[i];
  __syncthreads();
  int xi = tid & 31, cb = tid >> 5; // 8 channel-groups per pass
#pragma unroll
  for (int j = 0; j < 32; ++j) {
    int c = cb + j * 8;
    out[(n * CIN + c) * (HH * WW) + p0 + xi] = tr[c][xi];
  }
}

extern "C" void kernel_launch(void* const* d_in, const int* in_sizes, int n_in,
                              void* d_out, int out_size, void* d_ws, size_t ws_size,
                              hipStream_t stream) {
  const float* x  = (const float*)d_in[0];
  const float* w1 = (const float*)d_in[1]; // [32][4][256]
  const float* b1 = (const float*)d_in[2]; // [32][4]
  const float* w2 = (const float*)d_in[3]; // [32][4][4][3][3]
  const float* b2 = (const float*)d_in[4]; // [32][4]
  const float* w3 = (const float*)d_in[5]; // [32][256][4]
  const float* b3 = (const float*)d_in[6]; // [32][256]
  float* out = (float*)d_out;
  float* ws = (float*)d_ws;

  const int STATE = NN * HH * WW * CB; // 262144 floats = 1 MiB
  float* h1a = ws;
  float* h1b = ws + STATE;
  float* h2  = ws + 2 * STATE; // 32 MiB

  phaseA<<<dim3(HH, NN), 256, 0, stream>>>(x, w1, b1, h1a);
  for (int k = 0; k < NBLK; ++k) {
    const float* hin = (k & 1) ? h1b : h1a;
    float* hout = (k & 1) ? h1a : h1b;
    int kn = (k < NBLK - 1) ? k + 1 : NBLK - 1; // wrapped, unused on last
    phaseB<<<dim3(4, 4, NN), 256, 0, stream>>>(
        hin, hout, h2 + k * STATE,
        w2 + k * 144, b2 + k * CB, w3 + k * 1024, b3 + k * 256,
        w1 + kn * 1024, b1 + kn * CB, (k < NBLK - 1) ? 1 : 0);
  }
  phaseC<<<dim3((HH * WW) / PXT, NN), 256, 0, stream>>>(h2, w3, b3, out);
}

// Round 5
// 515.350 us; speedup vs baseline: 1.5954x; 1.5954x over previous
//
#include <hip/hip_runtime.h>

// 32 chained bottleneck blocks on x[16,256,64,64] fp32.
// Phase A: h1_0 = relu(W1_0 x + b1_0)           (reads x once)
// Phase B (x32): h2_k = relu(conv3x3 h1_k), store h2_k;
//                h1_{k+1} = relu(W1_{k+1} relu(W3_k h2_k + b3_k) + b1_{k+1})
//                fused; 256-ch tensor never hits memory.
// Phase C: out = sum_k relu(W3_k h2_k + b3_k)   (lane = channel)
//
// R4 lesson: v_readlane (VALU->SGPR->VALU) stalls; occupancy=1 exposed all
// latency. R1/R3 lesson: LDS pipe serializes broadcast weight reads (576
// b128/wave/step). R5: 8 pixels per thread + channel-split across wave
// halves -> each weight read feeds 8 pixels (72 FMA per 2.25 LDS reads);
// 2-address b128 broadcast = 2-way conflict = free (m136). Partials combined
// via XOR-swizzled float4 LDS (conflict-free b128).

#define NN 16
#define HH 64
#define WW 64
#define CIN 256
#define CB 4
#define NBLK 32
#define PXT 32  // pixels per phaseC block

__device__ __forceinline__ int pxs(int px) { return px ^ ((px >> 3) & 7); }

// ---------------- Phase A: h1_0 = relu(W1_0 . x + b1_0) ------------------
// grid (64,16): blockIdx.x = y, blockIdx.y = n. 256 threads.
__global__ __launch_bounds__(256) void phaseA(
    const float* __restrict__ x, const float* __restrict__ w1,
    const float* __restrict__ b1, float* __restrict__ h1out) {
  __shared__ float4 w1s[CIN];    // [c] -> o components
  __shared__ float4 part[4][WW]; // [chunk][px] -> o components
  int tid = threadIdx.x;
  for (int i = tid; i < CIN * CB; i += 256) {
    int o = i >> 8, c = i & 255;
    ((float*)&w1s[c])[o] = w1[i]; // w1 global layout [o][c]
  }
  __syncthreads();
  int y = blockIdx.x, n = blockIdx.y;
  int chunk = tid >> 6, px = tid & 63;
  int cbase = chunk * 64;
  const float* xp = x + ((n * CIN + cbase) * HH + y) * WW + px;
  float s0 = 0.f, s1 = 0.f, s2 = 0.f, s3 = 0.f;
#pragma unroll 8
  for (int i = 0; i < 64; ++i) {
    float xv = xp[i * HH * WW];
    float4 wv = w1s[cbase + i];
    s0 = fmaf(xv, wv.x, s0);
    s1 = fmaf(xv, wv.y, s1);
    s2 = fmaf(xv, wv.z, s2);
    s3 = fmaf(xv, wv.w, s3);
  }
  part[chunk][px] = make_float4(s0, s1, s2, s3);
  __syncthreads();
  int px2 = tid >> 2, o = tid & 3;
  float v = ((float*)&part[0][px2])[o] + ((float*)&part[1][px2])[o] +
            ((float*)&part[2][px2])[o] + ((float*)&part[3][px2])[o];
  v += b1[o];
  h1out[((n * HH + y) * WW + px2) * CB + o] = fmaxf(v, 0.f);
}

// ---------------- Phase B: one bottleneck step ---------------------------
// 16x16 pixel tile per block, 256 threads, grid (4,4,16) = 1 block/CU.
// Conv: thread = pixel. Fused expand+reduce: pg = tid&31 owns 8 pixels,
// q = tid>>5 owns 32 channels; weight b128 reads are 2-address per wave
// (free 2-way). comb[q][px] partials summed by thread=pixel at the end.
__global__ __launch_bounds__(256) void phaseB(
    const float* __restrict__ h1in, float* __restrict__ h1out,
    float* __restrict__ h2out,
    const float* __restrict__ w2, const float* __restrict__ b2,
    const float* __restrict__ w3, const float* __restrict__ b3,
    const float* __restrict__ w1n, const float* __restrict__ b1n,
    int compute_next) {
  __shared__ float4 wpk[CIN][2]; // [c][0]=w3[c][j], [c][1]=w1nT[c]  (8K)
  __shared__ float4 b3p[64];     // b3 packed by 4                   (1K)
  __shared__ __align__(16) float uni[8192]; // 32K union region
  float4* h2pv = (float4*)uni;            // [256] swizzled, 4K
  float4* combv = (float4*)uni;           // [8][256] swizzled, 32K
  float4 (*h1t)[18] = (float4(*)[18])uni; // 18x18 tile, 5.2K

  int tid = threadIdx.x;
  int tx = blockIdx.x, ty = blockIdx.y, n = blockIdx.z;
  int x0 = tx * 16, y0 = ty * 16;

  // stage packed weights (one c per thread)
  {
    int c = tid;
    wpk[c][0] = *(const float4*)&w3[c * 4]; // w3 [c][jout]
    float4 wt;
    wt.x = w1n[c];          // w1n global [o][c]
    wt.y = w1n[256 + c];
    wt.z = w1n[512 + c];
    wt.w = w1n[768 + c];
    wpk[c][1] = wt;
    if (tid < 64) b3p[tid] = *(const float4*)&b3[tid * 4];
  }
  // stage input tile with zero halo (into union region as h1t)
  for (int t = tid; t < 324; t += 256) {
    int cy = t / 18, cx = t % 18;
    int gy = y0 + cy - 1, gx = x0 + cx - 1;
    float4 v = make_float4(0.f, 0.f, 0.f, 0.f);
    if (gy >= 0 && gy < HH && gx >= 0 && gx < WW)
      v = *(const float4*)&h1in[((n * HH + gy) * WW + gx) * CB];
    h1t[cy][cx] = v;
  }
  __syncthreads(); // B1: tile + weights staged

  int lx = tid & 15, ly = tid >> 4;

  // 3x3 conv 4->4 + bias + relu; w2 [o][i][p] uniform -> hoisted s_loads
  float4 hacc = make_float4(b2[0], b2[1], b2[2], b2[3]);
#pragma unroll
  for (int p = 0; p < 9; ++p) {
    int dy = p / 3, dx = p % 3;
    float4 hv = h1t[ly + dy][lx + dx];
#pragma unroll
    for (int i = 0; i < 4; ++i) {
      float hvi = (i == 0) ? hv.x : (i == 1) ? hv.y : (i == 2) ? hv.z : hv.w;
      hacc.x = fmaf(hvi, w2[(0 * 4 + i) * 9 + p], hacc.x);
      hacc.y = fmaf(hvi, w2[(1 * 4 + i) * 9 + p], hacc.y);
      hacc.z = fmaf(hvi, w2[(2 * 4 + i) * 9 + p], hacc.z);
      hacc.w = fmaf(hvi, w2[(3 * 4 + i) * 9 + p], hacc.w);
    }
  }
  float4 h2 = make_float4(fmaxf(hacc.x, 0.f), fmaxf(hacc.y, 0.f),
                          fmaxf(hacc.z, 0.f), fmaxf(hacc.w, 0.f));

  int gy = y0 + ly, gx = x0 + lx;
  int pxg = (n * HH + gy) * WW + gx;
  *(float4*)&h2out[pxg * CB] = h2; // phaseC input, coalesced

  __syncthreads(); // B2: all h1t reads done -> safe to overwrite union
  h2pv[pxs(tid)] = h2;
  __syncthreads(); // B3: h2 tile staged

  int pg = tid & 31, q = tid >> 5; // 8 pixels, 32 channels per thread
  float4 h2r[8];
#pragma unroll
  for (int j = 0; j < 8; ++j) h2r[j] = h2pv[pxs(pg * 8 + j)];

  float4 tp[8];
#pragma unroll
  for (int j = 0; j < 8; ++j) tp[j] = make_float4(0.f, 0.f, 0.f, 0.f);

  int cbase = q * 32;
  for (int i4 = 0; i4 < 8; ++i4) { // 4 channels per iteration
    float4 bv = b3p[q * 8 + i4];
#pragma unroll
    for (int s = 0; s < 4; ++s) {
      int c = cbase + i4 * 4 + s;
      float b = (s == 0) ? bv.x : (s == 1) ? bv.y : (s == 2) ? bv.z : bv.w;
      float4 w3v = wpk[c][0];
      float4 wnv = wpk[c][1];
#pragma unroll
      for (int j = 0; j < 8; ++j) {
        float u = fmaf(h2r[j].x, w3v.x, b);
        u = fmaf(h2r[j].y, w3v.y, u);
        u = fmaf(h2r[j].z, w3v.z, u);
        u = fmaf(h2r[j].w, w3v.w, u);
        float v = fmaxf(u, 0.f);
        tp[j].x = fmaf(v, wnv.x, tp[j].x);
        tp[j].y = fmaf(v, wnv.y, tp[j].y);
        tp[j].z = fmaf(v, wnv.z, tp[j].z);
        tp[j].w = fmaf(v, wnv.w, tp[j].w);
      }
    }
  }

  __syncthreads(); // B4: all h2pv reads done -> safe to overwrite as comb
#pragma unroll
  for (int j = 0; j < 8; ++j)
    combv[q * 256 + pxs(pg * 8 + j)] = tp[j];
  __syncthreads(); // B5: partials staged

  if (compute_next) {
    float4 t = combv[0 * 256 + pxs(tid)];
#pragma unroll
    for (int qq = 1; qq < 8; ++qq) {
      float4 pv = combv[qq * 256 + pxs(tid)];
      t.x += pv.x; t.y += pv.y; t.z += pv.z; t.w += pv.w;
    }
    float4 r = make_float4(fmaxf(t.x + b1n[0], 0.f), fmaxf(t.y + b1n[1], 0.f),
                           fmaxf(t.z + b1n[2], 0.f), fmaxf(t.w + b1n[3], 0.f));
    *(float4*)&h1out[pxg * CB] = r;
  }
}

// ---------------- Phase C: acc = sum_k relu(W3_k h2_k + b3_k) ------------
// Lane = channel: tid = c, block covers PXT=32 consecutive pixels. Weights in
// registers (coalesced per-k loads), h2 broadcast from double-buffered LDS.
// Padded LDS transpose for coalesced stores. grid (128, 16).
__global__ __launch_bounds__(256, 4) void phaseC(
    const float* __restrict__ h2buf, const float* __restrict__ w3g,
    const float* __restrict__ b3g, float* __restrict__ out) {
  __shared__ float4 h2s[2][PXT];
  __shared__ float tr[CIN][PXT + 1]; // +1 pad: 2-way bank alias = free
  int tid = threadIdx.x;             // channel c
  int p0 = blockIdx.x * PXT;         // flat pixel y*64+x
  int n = blockIdx.y;
  float acc[PXT];
#pragma unroll
  for (int i = 0; i < PXT; ++i) acc[i] = 0.f;

  if (tid < PXT)
    h2s[0][tid] = *(const float4*)&h2buf[((0 * NN + n) * 4096 + p0 + tid) * 4];
  __syncthreads();

  for (int k = 0; k < NBLK; ++k) {
    float4 wv = *(const float4*)&w3g[(k * 256 + tid) * 4]; // coalesced
    float bv = b3g[k * 256 + tid];
    if (k + 1 < NBLK && tid < PXT)
      h2s[(k + 1) & 1][tid] =
          *(const float4*)&h2buf[(((k + 1) * NN + n) * 4096 + p0 + tid) * 4];
    const float4* hb = h2s[k & 1];
#pragma unroll
    for (int i = 0; i < PXT; ++i) {
      float4 h = hb[i]; // broadcast ds_read_b128
      float u = fmaf(h.w, wv.w,
                fmaf(h.z, wv.z, fmaf(h.y, wv.y, fmaf(h.x, wv.x, bv))));
      acc[i] += fmaxf(u, 0.f);
    }
    __syncthreads();
  }

  // transpose in LDS -> coalesced stores
#pragma unroll
  for (int i = 0; i < PXT; ++i) tr[tid][i] = acc[i];
  __syncthreads();
  int xi = tid & 31, cb = tid >> 5; // 8 channel-groups per pass
#pragma unroll
  for (int j = 0; j < 32; ++j) {
    int c = cb + j * 8;
    out[(n * CIN + c) * (HH * WW) + p0 + xi] = tr[c][xi];
  }
}

extern "C" void kernel_launch(void* const* d_in, const int* in_sizes, int n_in,
                              void* d_out, int out_size, void* d_ws, size_t ws_size,
                              hipStream_t stream) {
  const float* x  = (const float*)d_in[0];
  const float* w1 = (const float*)d_in[1]; // [32][4][256]
  const float* b1 = (const float*)d_in[2]; // [32][4]
  const float* w2 = (const float*)d_in[3]; // [32][4][4][3][3]
  const float* b2 = (const float*)d_in[4]; // [32][4]
  const float* w3 = (const float*)d_in[5]; // [32][256][4]
  const float* b3 = (const float*)d_in[6]; // [32][256]
  float* out = (float*)d_out;
  float* ws = (float*)d_ws;

  const int STATE = NN * HH * WW * CB; // 262144 floats = 1 MiB
  float* h1a = ws;
  float* h1b = ws + STATE;
  float* h2  = ws + 2 * STATE; // 32 MiB

  phaseA<<<dim3(HH, NN), 256, 0, stream>>>(x, w1, b1, h1a);
  for (int k = 0; k < NBLK; ++k) {
    const float* hin = (k & 1) ? h1b : h1a;
    float* hout = (k & 1) ? h1a : h1b;
    int kn = (k < NBLK - 1) ? k + 1 : NBLK - 1; // wrapped, unused on last
    phaseB<<<dim3(4, 4, NN), 256, 0, stream>>>(
        hin, hout, h2 + k * STATE,
        w2 + k * 144, b2 + k * CB, w3 + k * 1024, b3 + k * 256,
        w1 + kn * 1024, b1 + kn * CB, (k < NBLK - 1) ? 1 : 0);
  }
  phaseC<<<dim3((HH * WW) / PXT, NN), 256, 0, stream>>>(h2, w3, b3, out);
}

// Round 6
// 463.787 us; speedup vs baseline: 1.7728x; 1.1112x over previous
//
#include <hip/hip_runtime.h>

// 32 chained bottleneck blocks on x[16,256,64,64] fp32.
// Phase A: h1_0 = relu(W1_0 x + b1_0)           (reads x once)
// Phase B (x32): h2_k = relu(conv3x3 h1_k), store h2_k;
//                h1_{k+1} = relu(W1_{k+1} relu(W3_k h2_k + b3_k) + b1_{k+1})
//                fused; 256-ch tensor never hits memory.
// Phase C: out = sum_k relu(W3_k h2_k + b3_k)   (lane = channel)
//
// R5 lesson: weight delivery fixed (8-px reuse per read), but grid=256 ->
// 1 block/CU, 1 wave/SIMD: every staging load + barrier drain fully exposed.
// R6: 512 blocks (16x8 tiles) -> 2 blocks/CU, 8 waves/CU; 16-way channel
// split keeps 72 FMA per weight b128-pair; 3 barriers instead of 5.

#define NN 16
#define HH 64
#define WW 64
#define CIN 256
#define CB 4
#define NBLK 32
#define PXT 32  // pixels per phaseC block

__device__ __forceinline__ int pxs(int px) { return px ^ ((px >> 3) & 7); }

// ---------------- Phase A: h1_0 = relu(W1_0 . x + b1_0) ------------------
// grid (64,16): blockIdx.x = y, blockIdx.y = n. 256 threads.
__global__ __launch_bounds__(256) void phaseA(
    const float* __restrict__ x, const float* __restrict__ w1,
    const float* __restrict__ b1, float* __restrict__ h1out) {
  __shared__ float4 w1s[CIN];    // [c] -> o components
  __shared__ float4 part[4][WW]; // [chunk][px] -> o components
  int tid = threadIdx.x;
  for (int i = tid; i < CIN * CB; i += 256) {
    int o = i >> 8, c = i & 255;
    ((float*)&w1s[c])[o] = w1[i]; // w1 global layout [o][c]
  }
  __syncthreads();
  int y = blockIdx.x, n = blockIdx.y;
  int chunk = tid >> 6, px = tid & 63;
  int cbase = chunk * 64;
  const float* xp = x + ((n * CIN + cbase) * HH + y) * WW + px;
  float s0 = 0.f, s1 = 0.f, s2 = 0.f, s3 = 0.f;
#pragma unroll 8
  for (int i = 0; i < 64; ++i) {
    float xv = xp[i * HH * WW];
    float4 wv = w1s[cbase + i];
    s0 = fmaf(xv, wv.x, s0);
    s1 = fmaf(xv, wv.y, s1);
    s2 = fmaf(xv, wv.z, s2);
    s3 = fmaf(xv, wv.w, s3);
  }
  part[chunk][px] = make_float4(s0, s1, s2, s3);
  __syncthreads();
  int px2 = tid >> 2, o = tid & 3;
  float v = ((float*)&part[0][px2])[o] + ((float*)&part[1][px2])[o] +
            ((float*)&part[2][px2])[o] + ((float*)&part[3][px2])[o];
  v += b1[o];
  h1out[((n * HH + y) * WW + px2) * CB + o] = fmaxf(v, 0.f);
}

// ---------------- Phase B: one bottleneck step ---------------------------
// 16x8 pixel tile, 256 threads, grid (4,8,16) = 512 blocks = 2/CU.
// Conv: threads 0-127 = pixels. Fused expand+reduce: q = tid>>4 owns 16
// channels, pg = tid&15 owns 8 pixels (72 FMA per wpk b128 pair).
// comb[16][128] partials (XOR-swizzled, aliases h1t) summed by thread=pixel.
__global__ __launch_bounds__(256, 2) void phaseB(
    const float* __restrict__ h1in, float* __restrict__ h1out,
    float* __restrict__ h2out,
    const float* __restrict__ w2, const float* __restrict__ b2,
    const float* __restrict__ w3, const float* __restrict__ b3,
    const float* __restrict__ w1n, const float* __restrict__ b1n,
    int compute_next) {
  __shared__ float4 wpk[CIN][2];  // [c][0]=w3[c][j], [c][1]=w1nT[c]  (8K)
  __shared__ float4 b3p[64];      // b3 packed by 4                   (1K)
  __shared__ float4 h2sb[128];    // h2 tile, swizzled                (2K)
  __shared__ __align__(16) float4 uni[2048]; // 32K: comb[16][128] / h1t[10][18]
  float4 (*h1t)[18] = (float4(*)[18])uni;
  float4* comb = (float4*)uni;

  int tid = threadIdx.x;
  int tx = blockIdx.x, ty = blockIdx.y, n = blockIdx.z;
  int x0 = tx * 16, y0 = ty * 8;

  // stage packed weights (one c per thread)
  {
    int c = tid;
    wpk[c][0] = *(const float4*)&w3[c * 4]; // w3 [c][jout]
    float4 wt;
    wt.x = w1n[c];          // w1n global [o][c]
    wt.y = w1n[256 + c];
    wt.z = w1n[512 + c];
    wt.w = w1n[768 + c];
    wpk[c][1] = wt;
    if (tid < 64) b3p[tid] = *(const float4*)&b3[tid * 4];
  }
  // stage input tile with zero halo (10 rows x 18 cols)
  if (tid < 180) {
    int cy = tid / 18, cx = tid % 18;
    int gy = y0 + cy - 1, gx = x0 + cx - 1;
    float4 v = make_float4(0.f, 0.f, 0.f, 0.f);
    if (gy >= 0 && gy < HH && gx >= 0 && gx < WW)
      v = *(const float4*)&h1in[((n * HH + gy) * WW + gx) * CB];
    h1t[cy][cx] = v;
  }
  __syncthreads(); // B1: tile + weights staged

  // 3x3 conv 4->4 + bias + relu on threads 0-127 (one per pixel)
  if (tid < 128) {
    int lx = tid & 15, ly = tid >> 4;
    float4 hacc = make_float4(b2[0], b2[1], b2[2], b2[3]);
#pragma unroll
    for (int p = 0; p < 9; ++p) {
      int dy = p / 3, dx = p % 3;
      float4 hv = h1t[ly + dy][lx + dx];
#pragma unroll
      for (int i = 0; i < 4; ++i) {
        float hvi = (i == 0) ? hv.x : (i == 1) ? hv.y : (i == 2) ? hv.z : hv.w;
        hacc.x = fmaf(hvi, w2[(0 * 4 + i) * 9 + p], hacc.x);
        hacc.y = fmaf(hvi, w2[(1 * 4 + i) * 9 + p], hacc.y);
        hacc.z = fmaf(hvi, w2[(2 * 4 + i) * 9 + p], hacc.z);
        hacc.w = fmaf(hvi, w2[(3 * 4 + i) * 9 + p], hacc.w);
      }
    }
    float4 h2 = make_float4(fmaxf(hacc.x, 0.f), fmaxf(hacc.y, 0.f),
                            fmaxf(hacc.z, 0.f), fmaxf(hacc.w, 0.f));
    int gy = y0 + ly, gx = x0 + lx;
    int pxg = (n * HH + gy) * WW + gx;
    *(float4*)&h2out[pxg * CB] = h2; // phaseC input, coalesced
    h2sb[pxs(tid)] = h2;
  }
  __syncthreads(); // B2: h2 tile staged; h1t dead -> comb may overwrite

  int pg = tid & 15, q = tid >> 4; // 8 pixels, 16 channels per thread
  float4 h2r[8];
#pragma unroll
  for (int j = 0; j < 8; ++j) h2r[j] = h2sb[pxs(pg * 8 + j)];

  float4 tp[8];
#pragma unroll
  for (int j = 0; j < 8; ++j) tp[j] = make_float4(0.f, 0.f, 0.f, 0.f);

#pragma unroll
  for (int i4 = 0; i4 < 4; ++i4) { // 4 channels per iteration
    float4 bv = b3p[q * 4 + i4];
#pragma unroll
    for (int s = 0; s < 4; ++s) {
      int c = q * 16 + i4 * 4 + s;
      float b = (s == 0) ? bv.x : (s == 1) ? bv.y : (s == 2) ? bv.z : bv.w;
      float4 w3v = wpk[c][0];
      float4 wnv = wpk[c][1];
#pragma unroll
      for (int j = 0; j < 8; ++j) {
        float u = fmaf(h2r[j].x, w3v.x, b);
        u = fmaf(h2r[j].y, w3v.y, u);
        u = fmaf(h2r[j].z, w3v.z, u);
        u = fmaf(h2r[j].w, w3v.w, u);
        float v = fmaxf(u, 0.f);
        tp[j].x = fmaf(v, wnv.x, tp[j].x);
        tp[j].y = fmaf(v, wnv.y, tp[j].y);
        tp[j].z = fmaf(v, wnv.z, tp[j].z);
        tp[j].w = fmaf(v, wnv.w, tp[j].w);
      }
    }
  }

#pragma unroll
  for (int j = 0; j < 8; ++j)
    comb[q * 128 + pxs(pg * 8 + j)] = tp[j];
  __syncthreads(); // B3: partials staged

  if (compute_next && tid < 128) {
    int p = tid;
    float4 t = comb[pxs(p)];
#pragma unroll
    for (int qq = 1; qq < 16; ++qq) {
      float4 pv = comb[qq * 128 + pxs(p)];
      t.x += pv.x; t.y += pv.y; t.z += pv.z; t.w += pv.w;
    }
    float4 r = make_float4(fmaxf(t.x + b1n[0], 0.f), fmaxf(t.y + b1n[1], 0.f),
                           fmaxf(t.z + b1n[2], 0.f), fmaxf(t.w + b1n[3], 0.f));
    int gy = y0 + (p >> 4), gx = x0 + (p & 15);
    *(float4*)&h1out[((n * HH + gy) * WW + gx) * CB] = r;
  }
}

// ---------------- Phase C: acc = sum_k relu(W3_k h2_k + b3_k) ------------
// Lane = channel: tid = c, block covers PXT=32 consecutive pixels. Weights in
// registers (coalesced per-k loads), h2 broadcast from double-buffered LDS.
// Padded LDS transpose for coalesced stores. grid (128, 16).
__global__ __launch_bounds__(256, 4) void phaseC(
    const float* __restrict__ h2buf, const float* __restrict__ w3g,
    const float* __restrict__ b3g, float* __restrict__ out) {
  __shared__ float4 h2s[2][PXT];
  __shared__ float tr[CIN][PXT + 1]; // +1 pad: 2-way bank alias = free
  int tid = threadIdx.x;             // channel c
  int p0 = blockIdx.x * PXT;         // flat pixel y*64+x
  int n = blockIdx.y;
  float acc[PXT];
#pragma unroll
  for (int i = 0; i < PXT; ++i) acc[i] = 0.f;

  if (tid < PXT)
    h2s[0][tid] = *(const float4*)&h2buf[((0 * NN + n) * 4096 + p0 + tid) * 4];
  __syncthreads();

  for (int k = 0; k < NBLK; ++k) {
    float4 wv = *(const float4*)&w3g[(k * 256 + tid) * 4]; // coalesced
    float bv = b3g[k * 256 + tid];
    if (k + 1 < NBLK && tid < PXT)
      h2s[(k + 1) & 1][tid] =
          *(const float4*)&h2buf[(((k + 1) * NN + n) * 4096 + p0 + tid) * 4];
    const float4* hb = h2s[k & 1];
#pragma unroll
    for (int i = 0; i < PXT; ++i) {
      float4 h = hb[i]; // broadcast ds_read_b128
      float u = fmaf(h.w, wv.w,
                fmaf(h.z, wv.z, fmaf(h.y, wv.y, fmaf(h.x, wv.x, bv))));
      acc[i] += fmaxf(u, 0.f);
    }
    __syncthreads();
  }

  // transpose in LDS -> coalesced stores
#pragma unroll
  for (int i = 0; i < PXT; ++i) tr[tid][i] = acc[i];
  __syncthreads();
  int xi = tid & 31, cb = tid >> 5; // 8 channel-groups per pass
#pragma unroll
  for (int j = 0; j < 32; ++j) {
    int c = cb + j * 8;
    out[(n * CIN + c) * (HH * WW) + p0 + xi] = tr[c][xi];
  }
}

extern "C" void kernel_launch(void* const* d_in, const int* in_sizes, int n_in,
                              void* d_out, int out_size, void* d_ws, size_t ws_size,
                              hipStream_t stream) {
  const float* x  = (const float*)d_in[0];
  const float* w1 = (const float*)d_in[1]; // [32][4][256]
  const float* b1 = (const float*)d_in[2]; // [32][4]
  const float* w2 = (const float*)d_in[3]; // [32][4][4][3][3]
  const float* b2 = (const float*)d_in[4]; // [32][4]
  const float* w3 = (const float*)d_in[5]; // [32][256][4]
  const float* b3 = (const float*)d_in[6]; // [32][256]
  float* out = (float*)d_out;
  float* ws = (float*)d_ws;

  const int STATE = NN * HH * WW * CB; // 262144 floats = 1 MiB
  float* h1a = ws;
  float* h1b = ws + STATE;
  float* h2  = ws + 2 * STATE; // 32 MiB

  phaseA<<<dim3(HH, NN), 256, 0, stream>>>(x, w1, b1, h1a);
  for (int k = 0; k < NBLK; ++k) {
    const float* hin = (k & 1) ? h1b : h1a;
    float* hout = (k & 1) ? h1a : h1b;
    int kn = (k < NBLK - 1) ? k + 1 : NBLK - 1; // wrapped, unused on last
    phaseB<<<dim3(4, 8, NN), 256, 0, stream>>>(
        hin, hout, h2 + k * STATE,
        w2 + k * 144, b2 + k * CB, w3 + k * 1024, b3 + k * 256,
        w1 + kn * 1024, b1 + kn * CB, (k < NBLK - 1) ? 1 : 0);
  }
  phaseC<<<dim3((HH * WW) / PXT, NN), 256, 0, stream>>>(h2, w3, b3, out);
}